// Round 1
// baseline (160.034 us; speedup 1.0000x reference)
//
#include <hip/hip_runtime.h>
#include <math.h>

#define E_TYPES 20
#define NBLK 2
#define NANG 7
#define CS 384
#define CH 128
#define N_TOK (8 * 2048)
#define TOK 32
#define TPB 256
#define TPB_MAIN 512
#define KC 128
#define MAX_TILES (N_TOK / TOK + E_TYPES)   // 532
#define NPREP 64

// ---- workspace: int control region ----
#define HIST_OFF 0           // 64 x 20 per-block histograms
#define CNT_OFF 1536         // 20 counts
#define POFF_OFF 1600        // 21 padded offsets (multiples of TOK)
#define PERM_OFF 2048        // padded perm entries

// ---- workspace: fragment-packed split-bf16 weights (bytes) ----
// 1KB block = 64 lanes x 16B; element (n,k): lane = (n&15)|((k>>3&3)<<4), j=k&7
#define WT1_OFF (256 * 1024)                       // phase-1 concat [768x128] per e
#define WT1_SZ  (20 * 8 * 24 * 2048)               // e x nt(8) x kb(24) x (hi1KB+lo1KB)
#define WTR_OFF (WT1_OFF + WT1_SZ)                 // residual: e x m4(4) x nt(8) x kb(4)
// total end ~13.4 MB

typedef __attribute__((ext_vector_type(8))) short bfrag;
typedef __attribute__((ext_vector_type(4))) float f32x4;

__device__ __forceinline__ void split_bf16(float x, unsigned short& h, unsigned short& l) {
    unsigned int u = __float_as_uint(x);
    unsigned int hb = (u + 0x7FFFu + ((u >> 16) & 1u)) & 0xFFFF0000u;
    h = (unsigned short)(hb >> 16);
    float r = x - __uint_as_float(hb);
    unsigned int v = __float_as_uint(r);
    l = (unsigned short)((v + 0x7FFFu + ((v >> 16) & 1u)) >> 16);
}

// prep1: blocks [0,1600) convert weights to fragment-packed split-bf16;
// blocks [1600,1664) build the per-block token histogram.
__global__ void prep1(const float* __restrict__ Win, const float* __restrict__ Winit,
                      const float* __restrict__ Wb1, const float* __restrict__ Wb2,
                      const int* __restrict__ aatype, int* __restrict__ wsI,
                      unsigned short* __restrict__ wt) {
    __shared__ int lh[E_TYPES];
    int bid = blockIdx.x;
    int t = threadIdx.x;
    if (bid >= 1600) {   // histogram part
        int b2 = bid - 1600;
        if (t < E_TYPES) lh[t] = 0;
        __syncthreads();
        int idx = b2 * 256 + t;
        if (idx < N_TOK) atomicAdd(&lh[aatype[idx]], 1);
        __syncthreads();
        if (t < E_TYPES) wsI[HIST_OFF + b2 * E_TYPES + t] = lh[t];
        return;
    }
    int gid = bid * 256 + t;
    unsigned short h[8], l[8];
    if (gid < 245760) {          // phase-1 weights: 20*8*24 blocks x 64 lanes
        int lane = gid & 63;
        int bi = gid >> 6;
        int kb = bi % 24;
        int r = bi / 24;
        int nt = r & 7, e = r >> 3;
        int n = nt * 16 + (lane & 15);
        int k0 = kb * 32 + (lane >> 4) * 8;
        #pragma unroll
        for (int j = 0; j < 8; j++) {
            int k = k0 + j;
            float x = (k < CS) ? Win[((size_t)e * CS + k) * CH + n]
                               : Winit[((size_t)e * CS + (k - CS)) * CH + n];
            split_bf16(x, h[j], l[j]);
        }
        unsigned short* dst = wt + (WT1_OFF / 2) + (size_t)bi * 1024 + lane * 8;
        *(bfrag*)dst = *(bfrag*)h;
        *(bfrag*)(dst + 512) = *(bfrag*)l;
    } else {                     // residual weights: 20*4*8*4 blocks x 64 lanes
        gid -= 245760;
        int lane = gid & 63;
        int bi = gid >> 6;       // 0..2559
        int kb = bi & 3;
        int nt = (bi >> 2) & 7;
        int m4 = (bi >> 5) & 3;
        int e = bi >> 7;
        int b = m4 >> 1;
        const float* W = (m4 & 1) ? Wb2 : Wb1;
        int n = nt * 16 + (lane & 15);
        int k0 = kb * 32 + (lane >> 4) * 8;
        #pragma unroll
        for (int j = 0; j < 8; j++) {
            int k = k0 + j;
            float x = W[(((size_t)e * NBLK + b) * CH + k) * CH + n];
            split_bf16(x, h[j], l[j]);
        }
        unsigned short* dst = wt + (WTR_OFF / 2) + (size_t)bi * 1024 + lane * 8;
        *(bfrag*)dst = *(bfrag*)h;
        *(bfrag*)(dst + 512) = *(bfrag*)l;
    }
}

// Deterministic scatter (unchanged — verified correct).
__global__ void scatter_k(const int* __restrict__ aatype, int* ws) {
    __shared__ int lhist[NPREP * E_TYPES];
    __shared__ int counts[E_TYPES], poff[E_TYPES + 1], mybase[E_TYPES], lcur[E_TYPES];
    int t = threadIdx.x;
    int bid = blockIdx.x;
    for (int idx = t; idx < NPREP * E_TYPES; idx += TPB)
        lhist[idx] = ws[HIST_OFF + idx];
    if (t < E_TYPES) lcur[t] = 0;
    __syncthreads();
    if (t < E_TYPES) {
        int tot = 0, pre = 0;
        for (int b = 0; b < NPREP; b++) {
            int v = lhist[b * E_TYPES + t];
            tot += v;
            if (b < bid) pre += v;
        }
        counts[t] = tot;
        mybase[t] = pre;
    }
    __syncthreads();
    if (t == 0) {
        int off = 0;
        for (int e = 0; e < E_TYPES; e++) {
            poff[e] = off;
            off += (counts[e] + TOK - 1) & ~(TOK - 1);
        }
        poff[E_TYPES] = off;
    }
    __syncthreads();
    if (t < E_TYPES) mybase[t] += poff[t];
    __syncthreads();
    int idx = bid * blockDim.x + t;
    if (idx < N_TOK) {
        int e = aatype[idx];
        int r = atomicAdd(&lcur[e], 1);
        ws[PERM_OFF + mybase[e] + r] = idx;
    }
    if (bid == 0) {
        if (t < E_TYPES) ws[CNT_OFF + t] = counts[t];
        if (t == 0)
            for (int e = 0; e <= E_TYPES; e++) ws[POFF_OFF + e] = poff[e];
    }
}

#define MFMA(a, b, c) __builtin_amdgcn_mfma_f32_16x16x32_bf16((a), (b), (c), 0, 0, 0)

// 512 threads = 8 waves; wave w owns N-tile w (16 output cols), both 16-row
// M-tiles. Same per-block weight traffic as the 4-wave version, 2x the
// resident waves/CU (grid was the occupancy limiter at 2.1 blocks/CU).
__global__ __launch_bounds__(TPB_MAIN)
void angle_main(const float* __restrict__ s, const float* __restrict__ si,
                const float* __restrict__ b_in, const float* __restrict__ b_init2,
                const float* __restrict__ bb1, const float* __restrict__ bb2,
                const float* __restrict__ Wout, const float* __restrict__ b_out,
                const int* __restrict__ wsI, const unsigned short* __restrict__ wt,
                float* __restrict__ out)
{
    __shared__ unsigned short Ah[TOK][136];   // bf16-hi activations, padded rows
    __shared__ unsigned short Al[TOK][136];   // bf16-lo
    __shared__ float Hf[TOK][132];            // fp32 h for epilogue
    __shared__ float Of[TOK][16];
    __shared__ int ptok[TOK];

    int pos = blockIdx.x * TOK;
    if (pos >= wsI[POFF_OFF + E_TYPES]) return;
    int e = 0;
    while (e < E_TYPES - 1 && pos >= wsI[POFF_OFF + e + 1]) e++;
    int n = wsI[CNT_OFF + e] - (pos - wsI[POFF_OFF + e]);
    if (n > TOK) n = TOK;

    int t = threadIdx.x;
    if (t < TOK) ptok[t] = wsI[PERM_OFF + pos + ((t < n) ? t : 0)];

    int w = t >> 6, lane = t & 63;
    int lane15 = lane & 15, quad = lane >> 4;
    int nc = w * 16 + lane15;                 // my output column

    const bfrag* wt1 = (const bfrag*)((const char*)wt + WT1_OFF);
    const bfrag* wtr = (const bfrag*)((const char*)wt + WTR_OFF);

    f32x4 acc[2];    // [m-tile]; C layout: col=lane15, row=quad*4+reg
    {
        float bv = b_in[e * CH + nc] + b_init2[e * CH + nc];
        acc[0] = (f32x4){bv, bv, bv, bv};
        acc[1] = acc[0];
    }

    __syncthreads();   // ptok visible

    // ---- phase 1: h = [relu(s) relu(si)] @ [Win;Winit] + biases, K=768 ----
    // Staging: 16 threads/row x 8 floats; chunk c+1 prefetched into regs
    // while MFMAs run on chunk c (hides the gather latency).
    int srow = t >> 4;
    int scol = (t & 15) * 8;
    size_t rowoff = (size_t)ptok[srow] * CS + scol;
    float4 p0 = *(const float4*)(s + rowoff);
    float4 p1 = *(const float4*)(s + rowoff + 4);

    for (int c = 0; c < 6; c++) {
        {   // write the prefetched chunk (relu + split) to LDS
            float xv[8] = {p0.x, p0.y, p0.z, p0.w, p1.x, p1.y, p1.z, p1.w};
            unsigned short h8[8], l8[8];
            #pragma unroll
            for (int j = 0; j < 8; j++)
                split_bf16(fmaxf(xv[j], 0.f), h8[j], l8[j]);
            *(bfrag*)&Ah[srow][scol] = *(bfrag*)h8;
            *(bfrag*)&Al[srow][scol] = *(bfrag*)l8;
        }
        __syncthreads();
        if (c < 5) {   // prefetch next chunk under this chunk's MFMAs
            const float* src = (c + 1 < 3) ? s : si;
            int kb0 = ((c + 1 < 3) ? (c + 1) : (c - 2)) * KC;
            p0 = *(const float4*)(src + rowoff + kb0);
            p1 = *(const float4*)(src + rowoff + kb0 + 4);
        }
        #pragma unroll
        for (int ks = 0; ks < 4; ks++) {
            int kb = c * 4 + ks;
            int kl = ks * 32 + quad * 8;
            bfrag ah0 = *(const bfrag*)&Ah[lane15][kl];
            bfrag ah1 = *(const bfrag*)&Ah[16 + lane15][kl];
            bfrag al0 = *(const bfrag*)&Al[lane15][kl];
            bfrag al1 = *(const bfrag*)&Al[16 + lane15][kl];
            size_t b0 = ((size_t)(e * 8 + w) * 24 + kb) * 128;
            bfrag bh = wt1[b0 + lane];
            bfrag bl = wt1[b0 + 64 + lane];
            acc[0] = MFMA(ah0, bh, acc[0]);
            acc[0] = MFMA(ah0, bl, acc[0]);
            acc[0] = MFMA(al0, bh, acc[0]);
            acc[1] = MFMA(ah1, bh, acc[1]);
            acc[1] = MFMA(ah1, bl, acc[1]);
            acc[1] = MFMA(al1, bh, acc[1]);
        }
        __syncthreads();
    }

    // ---- 2 residual blocks ----
    for (int b = 0; b < NBLK; b++) {
        // relu(h) -> split bf16 LDS (from C layout)
        #pragma unroll
        for (int mt = 0; mt < 2; mt++) {
            f32x4 v = acc[mt];
            #pragma unroll
            for (int r = 0; r < 4; r++) {
                int m = mt * 16 + quad * 4 + r;
                unsigned short hh, ll;
                split_bf16(fmaxf(v[r], 0.f), hh, ll);
                Ah[m][nc] = hh;
                Al[m][nc] = ll;
            }
        }
        __syncthreads();

        f32x4 a2[2];
        {
            float bv = bb1[(e * NBLK + b) * CH + nc];
            a2[0] = (f32x4){bv, bv, bv, bv};
            a2[1] = a2[0];
        }
        #pragma unroll
        for (int ks = 0; ks < 4; ks++) {
            int kl = ks * 32 + quad * 8;
            bfrag ah0 = *(const bfrag*)&Ah[lane15][kl];
            bfrag ah1 = *(const bfrag*)&Ah[16 + lane15][kl];
            bfrag al0 = *(const bfrag*)&Al[lane15][kl];
            bfrag al1 = *(const bfrag*)&Al[16 + lane15][kl];
            size_t b0 = (((size_t)(e * 4 + 2 * b) * 8 + w) * 4 + ks) * 128;
            bfrag bh = wtr[b0 + lane], bl = wtr[b0 + 64 + lane];
            a2[0] = MFMA(ah0, bh, a2[0]);
            a2[0] = MFMA(ah0, bl, a2[0]);
            a2[0] = MFMA(al0, bh, a2[0]);
            a2[1] = MFMA(ah1, bh, a2[1]);
            a2[1] = MFMA(ah1, bl, a2[1]);
            a2[1] = MFMA(al1, bh, a2[1]);
        }
        __syncthreads();

        // relu(a1) -> split bf16 LDS
        #pragma unroll
        for (int mt = 0; mt < 2; mt++) {
            f32x4 v = a2[mt];
            #pragma unroll
            for (int r = 0; r < 4; r++) {
                int m = mt * 16 + quad * 4 + r;
                unsigned short hh, ll;
                split_bf16(fmaxf(v[r], 0.f), hh, ll);
                Ah[m][nc] = hh;
                Al[m][nc] = ll;
            }
        }
        __syncthreads();

        f32x4 a3[2];
        {
            float bv = bb2[(e * NBLK + b) * CH + nc];
            a3[0] = (f32x4){bv, bv, bv, bv};
            a3[1] = a3[0];
        }
        #pragma unroll
        for (int ks = 0; ks < 4; ks++) {
            int kl = ks * 32 + quad * 8;
            bfrag ah0 = *(const bfrag*)&Ah[lane15][kl];
            bfrag ah1 = *(const bfrag*)&Ah[16 + lane15][kl];
            bfrag al0 = *(const bfrag*)&Al[lane15][kl];
            bfrag al1 = *(const bfrag*)&Al[16 + lane15][kl];
            size_t b0 = (((size_t)(e * 4 + 2 * b + 1) * 8 + w) * 4 + ks) * 128;
            bfrag bh = wtr[b0 + lane], bl = wtr[b0 + 64 + lane];
            a3[0] = MFMA(ah0, bh, a3[0]);
            a3[0] = MFMA(ah0, bl, a3[0]);
            a3[0] = MFMA(al0, bh, a3[0]);
            a3[1] = MFMA(ah1, bh, a3[1]);
            a3[1] = MFMA(ah1, bl, a3[1]);
            a3[1] = MFMA(al1, bh, a3[1]);
        }
        acc[0] += a3[0];
        acc[1] += a3[1];
        __syncthreads();
    }

    // ---- epilogue: relu(h) fp32 -> LDS ----
    #pragma unroll
    for (int mt = 0; mt < 2; mt++) {
        f32x4 v = acc[mt];
        #pragma unroll
        for (int r = 0; r < 4; r++)
            Hf[mt * 16 + quad * 4 + r][nc] = fmaxf(v[r], 0.f);
    }
    __syncthreads();

    // ---- out = relu(h) @ Wout + b_out (128 -> 14), 4-way partials ----
    const float* WoutE = Wout + (size_t)e * CH * (NANG * 2);
    const float* boutE = b_out + (size_t)e * (NANG * 2);
    for (int idx = t; idx < n * (NANG * 2); idx += TPB_MAIN) {
        int i = idx / (NANG * 2);
        int o = idx - i * (NANG * 2);
        float v0 = boutE[o], v1 = 0.f, v2 = 0.f, v3 = 0.f;
        #pragma unroll 4
        for (int k = 0; k < CH; k += 4) {
            v0 = fmaf(Hf[i][k],     WoutE[(size_t)k * (NANG * 2) + o],       v0);
            v1 = fmaf(Hf[i][k + 1], WoutE[(size_t)(k + 1) * (NANG * 2) + o], v1);
            v2 = fmaf(Hf[i][k + 2], WoutE[(size_t)(k + 2) * (NANG * 2) + o], v2);
            v3 = fmaf(Hf[i][k + 3], WoutE[(size_t)(k + 3) * (NANG * 2) + o], v3);
        }
        Of[i][o] = (v0 + v1) + (v2 + v3);
    }
    __syncthreads();

    // ---- pair-normalize and store ----
    for (int idx = t; idx < n * NANG; idx += TPB_MAIN) {
        int i = idx / NANG;
        int a = idx - i * NANG;
        float x = Of[i][2 * a];
        float y = Of[i][2 * a + 1];
        float nr = fmaxf(sqrtf(x * x + y * y), 1e-12f);
        size_t base = (size_t)ptok[i] * (NANG * 2) + 2 * a;
        out[base]     = x / nr;
        out[base + 1] = y / nr;
    }
}

extern "C" void kernel_launch(void* const* d_in, const int* in_sizes, int n_in,
                              void* d_out, int out_size, void* d_ws, size_t ws_size,
                              hipStream_t stream) {
    const float* s       = (const float*)d_in[0];
    const float* s_init  = (const float*)d_in[1];
    const int*   aatype  = (const int*)d_in[2];
    const float* Win     = (const float*)d_in[3];
    const float* b_in    = (const float*)d_in[4];
    const float* Winit   = (const float*)d_in[5];
    const float* b_init2 = (const float*)d_in[6];
    const float* Wb1     = (const float*)d_in[7];
    const float* bb1     = (const float*)d_in[8];
    const float* Wb2     = (const float*)d_in[9];
    const float* bb2     = (const float*)d_in[10];
    const float* Wout    = (const float*)d_in[11];
    const float* b_out   = (const float*)d_in[12];
    int* wsI = (int*)d_ws;
    unsigned short* wt = (unsigned short*)d_ws;
    float* out = (float*)d_out;

    hipLaunchKernelGGL(prep1, dim3(1664), dim3(256), 0, stream,
                       Win, Winit, Wb1, Wb2, aatype, wsI, wt);
    hipLaunchKernelGGL(scatter_k, dim3(NPREP), dim3(TPB), 0, stream, aatype, wsI);
    hipLaunchKernelGGL(angle_main, dim3(MAX_TILES), dim3(TPB_MAIN), 0, stream,
                       s, s_init, b_in, b_init2, bb1, bb2, Wout, b_out,
                       wsI, wt, out);
}

// Round 2
// 155.605 us; speedup vs baseline: 1.0285x; 1.0285x over previous
//
#include <hip/hip_runtime.h>
#include <math.h>

#define E_TYPES 20
#define NBLK 2
#define NANG 7
#define CS 384
#define CH 128
#define N_TOK (8 * 2048)
#define TOK 32
#define TPB 256
#define TPB_MAIN 512
#define KC 128
#define MAX_TILES (N_TOK / TOK + E_TYPES)   // 532
#define NPREP 64

// ---- workspace: int control region ----
#define HIST_OFF 0           // 64 x 20 per-block histograms

// ---- workspace: fragment-packed split-bf16 weights (bytes) ----
// 1KB block = 64 lanes x 16B; element (n,k): lane = (n&15)|((k>>3&3)<<4), j=k&7
#define WT1_OFF (256 * 1024)                       // phase-1 concat [768x128] per e
#define WT1_SZ  (20 * 8 * 24 * 2048)               // e x nt(8) x kb(24) x (hi1KB+lo1KB)
#define WTR_OFF (WT1_OFF + WT1_SZ)                 // residual: e x m4(4) x nt(8) x kb(4)
// total end ~13.4 MB

typedef __attribute__((ext_vector_type(8))) short bfrag;
typedef __attribute__((ext_vector_type(4))) float f32x4;
typedef unsigned short (*arr136)[136];

__device__ __forceinline__ void split_bf16(float x, unsigned short& h, unsigned short& l) {
    unsigned int u = __float_as_uint(x);
    unsigned int hb = (u + 0x7FFFu + ((u >> 16) & 1u)) & 0xFFFF0000u;
    h = (unsigned short)(hb >> 16);
    float r = x - __uint_as_float(hb);
    unsigned int v = __float_as_uint(r);
    l = (unsigned short)((v + 0x7FFFu + ((v >> 16) & 1u)) >> 16);
}

// prep1: blocks [0,1600) convert weights to fragment-packed split-bf16;
// blocks [1600,1664) build the per-block token histogram.
__global__ void prep1(const float* __restrict__ Win, const float* __restrict__ Winit,
                      const float* __restrict__ Wb1, const float* __restrict__ Wb2,
                      const int* __restrict__ aatype, int* __restrict__ wsI,
                      unsigned short* __restrict__ wt) {
    __shared__ int lh[E_TYPES];
    int bid = blockIdx.x;
    int t = threadIdx.x;
    if (bid >= 1600) {   // histogram part
        int b2 = bid - 1600;
        if (t < E_TYPES) lh[t] = 0;
        __syncthreads();
        int idx = b2 * 256 + t;
        if (idx < N_TOK) atomicAdd(&lh[aatype[idx]], 1);
        __syncthreads();
        if (t < E_TYPES) wsI[HIST_OFF + b2 * E_TYPES + t] = lh[t];
        return;
    }
    int gid = bid * 256 + t;
    unsigned short h[8], l[8];
    if (gid < 245760) {          // phase-1 weights: 20*8*24 blocks x 64 lanes
        int lane = gid & 63;
        int bi = gid >> 6;
        int kb = bi % 24;
        int r = bi / 24;
        int nt = r & 7, e = r >> 3;
        int n = nt * 16 + (lane & 15);
        int k0 = kb * 32 + (lane >> 4) * 8;
        #pragma unroll
        for (int j = 0; j < 8; j++) {
            int k = k0 + j;
            float x = (k < CS) ? Win[((size_t)e * CS + k) * CH + n]
                               : Winit[((size_t)e * CS + (k - CS)) * CH + n];
            split_bf16(x, h[j], l[j]);
        }
        unsigned short* dst = wt + (WT1_OFF / 2) + (size_t)bi * 1024 + lane * 8;
        *(bfrag*)dst = *(bfrag*)h;
        *(bfrag*)(dst + 512) = *(bfrag*)l;
    } else {                     // residual weights: 20*4*8*4 blocks x 64 lanes
        gid -= 245760;
        int lane = gid & 63;
        int bi = gid >> 6;       // 0..2559
        int kb = bi & 3;
        int nt = (bi >> 2) & 7;
        int m4 = (bi >> 5) & 3;
        int e = bi >> 7;
        int b = m4 >> 1;
        const float* W = (m4 & 1) ? Wb2 : Wb1;
        int n = nt * 16 + (lane & 15);
        int k0 = kb * 32 + (lane >> 4) * 8;
        #pragma unroll
        for (int j = 0; j < 8; j++) {
            int k = k0 + j;
            float x = W[(((size_t)e * NBLK + b) * CH + k) * CH + n];
            split_bf16(x, h[j], l[j]);
        }
        unsigned short* dst = wt + (WTR_OFF / 2) + (size_t)bi * 1024 + lane * 8;
        *(bfrag*)dst = *(bfrag*)h;
        *(bfrag*)(dst + 512) = *(bfrag*)l;
    }
}

#define MFMA(a, b, c) __builtin_amdgcn_mfma_f32_16x16x32_bf16((a), (b), (c), 0, 0, 0)

// 512 threads = 8 waves; wave w owns N-tile w. Scatter is derived in-block
// from the per-chunk histograms (no scatter kernel). Double-buffered LDS:
// one barrier per pipeline stage (14 total vs 21). XCD-chunked swizzle
// clusters same-e tiles per XCD so weight fragments stay L2-resident.
__global__ __launch_bounds__(TPB_MAIN)
void angle_main(const float* __restrict__ s, const float* __restrict__ si,
                const float* __restrict__ b_in, const float* __restrict__ b_init2,
                const float* __restrict__ bb1, const float* __restrict__ bb2,
                const float* __restrict__ Wout, const float* __restrict__ b_out,
                const int* __restrict__ aatype,
                const int* __restrict__ wsI, const unsigned short* __restrict__ wt,
                float* __restrict__ out)
{
    // LDS pool: two (Ah,Al) buffers of [32][136] u16; epilogue Hf/Of overlap.
    #define BUFSZ 17408
    __shared__ __align__(16) char pool[2 * BUFSZ];
    __shared__ int ptok[TOK];
    __shared__ int cntS[E_TYPES];

    arr136 AH0 = (arr136)(pool);
    arr136 AL0 = (arr136)(pool + 8704);
    arr136 AH1 = (arr136)(pool + BUFSZ);
    arr136 AL1 = (arr136)(pool + BUFSZ + 8704);
    float (*Hf)[132] = (float (*)[132])(pool);
    float (*Of)[16]  = (float (*)[16])(pool + BUFSZ);

    int t = threadIdx.x;
    int w = t >> 6, lane = t & 63;
    int lane15 = lane & 15, quad = lane >> 4;

    // XCD-chunked bijective swizzle: tiles are e-sorted; give each XCD a
    // contiguous tile range so its weight working set fits its 4MB L2.
    int bid = blockIdx.x;
    const int q = MAX_TILES >> 3, r = MAX_TILES & 7;   // 66, 4
    int xcd = bid & 7, sub = bid >> 3;
    int tile = (xcd < r ? xcd * (q + 1) : r * (q + 1) + (xcd - r) * q) + sub;

    // wave0: per-type counts from the 64x20 chunk histograms
    if (w == 0 && lane < E_TYPES) {
        int c = 0;
        #pragma unroll
        for (int b = 0; b < NPREP; b++) c += wsI[HIST_OFF + b * E_TYPES + lane];
        cntS[lane] = c;
    }
    __syncthreads();

    int pos = tile * TOK;
    int e = -1, poff_e = 0;
    {
        int acc = 0;
        #pragma unroll
        for (int ee = 0; ee < E_TYPES; ee++) {
            int pad = (cntS[ee] + TOK - 1) & ~(TOK - 1);
            if (e < 0 && pos < acc + pad) { e = ee; poff_e = acc; }
            acc += pad;
        }
        if (pos >= acc) return;     // beyond padded total (uniform exit)
    }
    int pos_in = pos - poff_e;
    int cnt_e = cntS[e];
    int n = cnt_e - pos_in; if (n > TOK) n = TOK;

    // wave0: rank-scan aatype to find tokens with rank [pos_in, pos_in+n) of type e
    if (w == 0) {
        int hb = wsI[HIST_OFF + lane * E_TYPES + e];     // chunk count (64 chunks)
        int inc = hb;
        #pragma unroll
        for (int d = 1; d < 64; d <<= 1) { int v = __shfl_up(inc, d); if (lane >= d) inc += v; }
        int pre = inc - hb;                               // exclusive prefix
        unsigned long long mle = __ballot(pre <= pos_in);
        int cb = 63 - __clzll(mle);                       // chunk containing rank pos_in
        int running = __shfl(pre, cb);
        int base = cb * 256;
        int lim = pos_in + n;
        while (running < lim && base < N_TOK) {
            const int4 a4 = *(const int4*)&aatype[base + lane * 4];
            int m0 = (a4.x == e), m1 = (a4.y == e), m2 = (a4.z == e), m3 = (a4.w == e);
            int c = m0 + m1 + m2 + m3;
            int incl = c;
            #pragma unroll
            for (int d = 1; d < 64; d <<= 1) { int v = __shfl_up(incl, d); if (lane >= d) incl += v; }
            int rk = running + incl - c;
            int tk = base + lane * 4;
            if (m0) { if (rk >= pos_in && rk < lim) ptok[rk - pos_in] = tk;     rk++; }
            if (m1) { if (rk >= pos_in && rk < lim) ptok[rk - pos_in] = tk + 1; rk++; }
            if (m2) { if (rk >= pos_in && rk < lim) ptok[rk - pos_in] = tk + 2; rk++; }
            if (m3) { if (rk >= pos_in && rk < lim) ptok[rk - pos_in] = tk + 3; rk++; }
            running += __shfl(incl, 63);
            base += 256;
        }
        int t0 = ptok[0];
        if (lane >= n && lane < TOK) ptok[lane] = t0;     // pad with dup token
    }
    __syncthreads();

    int nc = w * 16 + lane15;                 // my output column
    const bfrag* wt1 = (const bfrag*)((const char*)wt + WT1_OFF);
    const bfrag* wtr = (const bfrag*)((const char*)wt + WTR_OFF);

    f32x4 acc[2];    // [m-tile]; C layout: col=lane15, row=quad*4+reg
    {
        float bv = b_in[e * CH + nc] + b_init2[e * CH + nc];
        acc[0] = (f32x4){bv, bv, bv, bv};
        acc[1] = acc[0];
    }

    // ---- phase 1: h = [relu(s) relu(si)] @ [Win;Winit] + biases, K=768 ----
    int srow = t >> 4;
    int scol = (t & 15) * 8;
    size_t rowoff = (size_t)ptok[srow] * CS + scol;
    float4 p0 = *(const float4*)(s + rowoff);
    float4 p1 = *(const float4*)(s + rowoff + 4);
    size_t wb = (size_t)(e * 8 + w) * 24;
    bfrag pbh = wt1[wb * 128 + lane];                 // prefetch chunk0 ks0 weights
    bfrag pbl = wt1[wb * 128 + 64 + lane];

    #pragma unroll
    for (int c = 0; c < 6; c++) {
        arr136 WAH = (c & 1) ? AH1 : AH0;
        arr136 WAL = (c & 1) ? AL1 : AL0;
        {   // write the prefetched chunk (relu + split) to LDS
            float xv[8] = {p0.x, p0.y, p0.z, p0.w, p1.x, p1.y, p1.z, p1.w};
            unsigned short h8[8], l8[8];
            #pragma unroll
            for (int j = 0; j < 8; j++)
                split_bf16(fmaxf(xv[j], 0.f), h8[j], l8[j]);
            *(bfrag*)&WAH[srow][scol] = *(bfrag*)h8;
            *(bfrag*)&WAL[srow][scol] = *(bfrag*)l8;
        }
        if (c < 5) {   // prefetch next chunk activations before the barrier
            const float* src = (c + 1 < 3) ? s : si;
            int kb0 = ((c + 1 < 3) ? (c + 1) : (c - 2)) * KC;
            p0 = *(const float4*)(src + rowoff + kb0);
            p1 = *(const float4*)(src + rowoff + kb0 + 4);
        }
        __syncthreads();
        #pragma unroll
        for (int ks = 0; ks < 4; ks++) {
            int kb = c * 4 + ks;
            bfrag bh = ks ? wt1[(wb + kb) * 128 + lane]      : pbh;
            bfrag bl = ks ? wt1[(wb + kb) * 128 + 64 + lane] : pbl;
            int kl = ks * 32 + quad * 8;
            bfrag ah0 = *(const bfrag*)&WAH[lane15][kl];
            bfrag ah1 = *(const bfrag*)&WAH[16 + lane15][kl];
            bfrag al0 = *(const bfrag*)&WAL[lane15][kl];
            bfrag al1 = *(const bfrag*)&WAL[16 + lane15][kl];
            acc[0] = MFMA(ah0, bh, acc[0]);
            acc[0] = MFMA(ah0, bl, acc[0]);
            acc[0] = MFMA(al0, bh, acc[0]);
            acc[1] = MFMA(ah1, bh, acc[1]);
            acc[1] = MFMA(ah1, bl, acc[1]);
            acc[1] = MFMA(al1, bh, acc[1]);
        }
        if (c < 5) {   // prefetch next chunk ks0 weights (covers barrier + write)
            pbh = wt1[(wb + (c + 1) * 4) * 128 + lane];
            pbl = wt1[(wb + (c + 1) * 4) * 128 + 64 + lane];
        }
    }

    // ---- residual blocks: 4 GEMMs, one barrier each ----
    {
        size_t g0 = ((size_t)(e * 4) * 8 + w) * 4;
        pbh = wtr[g0 * 128 + lane];
        pbl = wtr[g0 * 128 + 64 + lane];
    }
    f32x4 cur[2] = {acc[0], acc[1]};
    #pragma unroll
    for (int g = 0; g < 4; g++) {
        arr136 WAH = (g & 1) ? AH1 : AH0;
        arr136 WAL = (g & 1) ? AL1 : AL0;
        #pragma unroll
        for (int mt = 0; mt < 2; mt++) {
            f32x4 v = cur[mt];
            #pragma unroll
            for (int rr = 0; rr < 4; rr++) {
                unsigned short hh, ll;
                split_bf16(fmaxf(v[rr], 0.f), hh, ll);
                WAH[mt * 16 + quad * 4 + rr][nc] = hh;
                WAL[mt * 16 + quad * 4 + rr][nc] = ll;
            }
        }
        __syncthreads();
        float bv = (g & 1) ? bb2[(e * NBLK + (g >> 1)) * CH + nc]
                           : bb1[(e * NBLK + (g >> 1)) * CH + nc];
        f32x4 r0 = (f32x4){bv, bv, bv, bv}, r1 = r0;
        size_t wgb = ((size_t)(e * 4 + g) * 8 + w) * 4;
        #pragma unroll
        for (int ks = 0; ks < 4; ks++) {
            bfrag bh = ks ? wtr[(wgb + ks) * 128 + lane]      : pbh;
            bfrag bl = ks ? wtr[(wgb + ks) * 128 + 64 + lane] : pbl;
            int kl = ks * 32 + quad * 8;
            bfrag ah0 = *(const bfrag*)&WAH[lane15][kl];
            bfrag ah1 = *(const bfrag*)&WAH[16 + lane15][kl];
            bfrag al0 = *(const bfrag*)&WAL[lane15][kl];
            bfrag al1 = *(const bfrag*)&WAL[16 + lane15][kl];
            r0 = MFMA(ah0, bh, r0);
            r0 = MFMA(ah0, bl, r0);
            r0 = MFMA(al0, bh, r0);
            r1 = MFMA(ah1, bh, r1);
            r1 = MFMA(ah1, bl, r1);
            r1 = MFMA(al1, bh, r1);
        }
        if (g < 3) {
            size_t nb = ((size_t)(e * 4 + g + 1) * 8 + w) * 4;
            pbh = wtr[nb * 128 + lane];
            pbl = wtr[nb * 128 + 64 + lane];
        }
        if (g & 1) { acc[0] += r0; acc[1] += r1; cur[0] = acc[0]; cur[1] = acc[1]; }
        else       { cur[0] = r0; cur[1] = r1; }
    }

    // ---- epilogue: relu(h) fp32 -> LDS (overlaps buf0; G2 readers done) ----
    #pragma unroll
    for (int mt = 0; mt < 2; mt++) {
        f32x4 v = acc[mt];
        #pragma unroll
        for (int rr = 0; rr < 4; rr++)
            Hf[mt * 16 + quad * 4 + rr][nc] = fmaxf(v[rr], 0.f);
    }
    __syncthreads();

    // ---- out = relu(h) @ Wout + b_out (128 -> 14), 4-way partials ----
    const float* WoutE = Wout + (size_t)e * CH * (NANG * 2);
    const float* boutE = b_out + (size_t)e * (NANG * 2);
    for (int idx = t; idx < n * (NANG * 2); idx += TPB_MAIN) {
        int i = idx / (NANG * 2);
        int o = idx - i * (NANG * 2);
        float v0 = boutE[o], v1 = 0.f, v2 = 0.f, v3 = 0.f;
        #pragma unroll 4
        for (int k = 0; k < CH; k += 4) {
            v0 = fmaf(Hf[i][k],     WoutE[(size_t)k * (NANG * 2) + o],       v0);
            v1 = fmaf(Hf[i][k + 1], WoutE[(size_t)(k + 1) * (NANG * 2) + o], v1);
            v2 = fmaf(Hf[i][k + 2], WoutE[(size_t)(k + 2) * (NANG * 2) + o], v2);
            v3 = fmaf(Hf[i][k + 3], WoutE[(size_t)(k + 3) * (NANG * 2) + o], v3);
        }
        Of[i][o] = (v0 + v1) + (v2 + v3);
    }
    __syncthreads();

    // ---- pair-normalize and store ----
    for (int idx = t; idx < n * NANG; idx += TPB_MAIN) {
        int i = idx / NANG;
        int a = idx - i * NANG;
        float x = Of[i][2 * a];
        float y = Of[i][2 * a + 1];
        float nr = fmaxf(sqrtf(x * x + y * y), 1e-12f);
        size_t base = (size_t)ptok[i] * (NANG * 2) + 2 * a;
        out[base]     = x / nr;
        out[base + 1] = y / nr;
    }
}

extern "C" void kernel_launch(void* const* d_in, const int* in_sizes, int n_in,
                              void* d_out, int out_size, void* d_ws, size_t ws_size,
                              hipStream_t stream) {
    const float* s       = (const float*)d_in[0];
    const float* s_init  = (const float*)d_in[1];
    const int*   aatype  = (const int*)d_in[2];
    const float* Win     = (const float*)d_in[3];
    const float* b_in    = (const float*)d_in[4];
    const float* Winit   = (const float*)d_in[5];
    const float* b_init2 = (const float*)d_in[6];
    const float* Wb1     = (const float*)d_in[7];
    const float* bb1     = (const float*)d_in[8];
    const float* Wb2     = (const float*)d_in[9];
    const float* bb2     = (const float*)d_in[10];
    const float* Wout    = (const float*)d_in[11];
    const float* b_out   = (const float*)d_in[12];
    int* wsI = (int*)d_ws;
    unsigned short* wt = (unsigned short*)d_ws;
    float* out = (float*)d_out;

    hipLaunchKernelGGL(prep1, dim3(1664), dim3(256), 0, stream,
                       Win, Winit, Wb1, Wb2, aatype, wsI, wt);
    hipLaunchKernelGGL(angle_main, dim3(MAX_TILES), dim3(TPB_MAIN), 0, stream,
                       s, s_init, b_in, b_init2, bb1, bb2, Wout, b_out,
                       aatype, wsI, wt, out);
}